// Round 1
// baseline (156.386 us; speedup 1.0000x reference)
//
#include <hip/hip_runtime.h>

// GatingNetwork: fused router GEMM + softmax + double top-k
// x: [16384, 2048] f32, W: [64, 2048] f32
// out (f32 flat): topk_idx[16384,2] | topk_weights[16384,2] | probs[16384,64] | topc_idx[16384,8]

constexpr int Bq = 16384;
constexpr int Dk = 2048;
constexpr int Me = 64;
constexpr int BM = 32;   // rows per block
constexpr int BK = 64;   // k-tile
constexpr int LD = BK + 4;  // padded leading dim (keeps 16B align, breaks bank aliasing)

constexpr size_t OFF_TOPK_IDX = 0;
constexpr size_t OFF_TOPK_W   = (size_t)Bq * 2;            // 32768
constexpr size_t OFF_PROBS    = (size_t)Bq * 4;            // 65536
constexpr size_t OFF_TOPC_IDX = (size_t)Bq * 4 + (size_t)Bq * 64;  // 1114112

__global__ __launch_bounds__(256, 2)
void gating_fused(const float* __restrict__ x, const float* __restrict__ W,
                  float* __restrict__ out) {
  __shared__ float xs[BM][LD];
  __shared__ float ws[Me][LD];

  const int tid   = threadIdx.x;
  const int row_t = tid >> 4;   // 0..15
  const int col_t = tid & 15;   // 0..15
  const int rowBase = blockIdx.x * BM;

  float acc[2][4];
  #pragma unroll
  for (int i = 0; i < 2; ++i)
    #pragma unroll
    for (int j = 0; j < 4; ++j) acc[i][j] = 0.f;

  for (int k0 = 0; k0 < Dk; k0 += BK) {
    // stage x tile: 32x64 f32 = 512 float4, 2 per thread (coalesced)
    #pragma unroll
    for (int i = 0; i < 2; ++i) {
      int f4 = i * 256 + tid;
      int r  = f4 >> 4;          // 0..31
      int kk = (f4 & 15) << 2;   // 0..60
      float4 v = *reinterpret_cast<const float4*>(x + (size_t)(rowBase + r) * Dk + k0 + kk);
      *reinterpret_cast<float4*>(&xs[r][kk]) = v;
    }
    // stage W tile: 64x64 f32 = 1024 float4, 4 per thread
    #pragma unroll
    for (int i = 0; i < 4; ++i) {
      int f4 = i * 256 + tid;
      int c  = f4 >> 4;          // 0..63
      int kk = (f4 & 15) << 2;
      float4 v = *reinterpret_cast<const float4*>(W + (size_t)c * Dk + k0 + kk);
      *reinterpret_cast<float4*>(&ws[c][kk]) = v;
    }
    __syncthreads();

    #pragma unroll
    for (int kk = 0; kk < BK; kk += 4) {
      float4 xv[2];
      xv[0] = *reinterpret_cast<const float4*>(&xs[row_t][kk]);
      xv[1] = *reinterpret_cast<const float4*>(&xs[row_t + 16][kk]);
      float4 wv[4];
      #pragma unroll
      for (int j = 0; j < 4; ++j)
        wv[j] = *reinterpret_cast<const float4*>(&ws[col_t + 16 * j][kk]);
      #pragma unroll
      for (int i = 0; i < 2; ++i) {
        #pragma unroll
        for (int j = 0; j < 4; ++j) {
          float a = acc[i][j];
          a = fmaf(xv[i].x, wv[j].x, a);
          a = fmaf(xv[i].y, wv[j].y, a);
          a = fmaf(xv[i].z, wv[j].z, a);
          a = fmaf(xv[i].w, wv[j].w, a);
          acc[i][j] = a;
        }
      }
    }
    __syncthreads();
  }

  // scatter logits to LDS for per-row epilogue (reuse xs: 32x64 fits in [32][68])
  #pragma unroll
  for (int i = 0; i < 2; ++i)
    #pragma unroll
    for (int j = 0; j < 4; ++j)
      xs[row_t + 16 * i][col_t + 16 * j] = acc[i][j];
  __syncthreads();

  if (tid < BM) {
    const int r = tid;
    const size_t grow = (size_t)rowBase + r;

    // pass 1: max
    float mx = -3.4e38f;
    for (int c = 0; c < Me; ++c) mx = fmaxf(mx, xs[r][c]);
    // pass 2: sum of exp
    float sum = 0.f;
    for (int c = 0; c < Me; ++c) sum += expf(xs[r][c] - mx);
    const float inv = 1.f / (sum + 1e-12f);
    // pass 3: write probs
    float* pr = out + OFF_PROBS + grow * 64;
    for (int c = 0; c < Me; ++c) pr[c] = expf(xs[r][c] - mx) * inv;

    // top-8 via 8 masked argmax passes; ascending scan + strict '>' matches
    // jax/np tie-break (lowest index first). top-2 = ranks 0,1 (already sorted).
    unsigned long long taken = 0ull;
    float tv0 = 0.f, tv1 = 0.f;
    for (int rank = 0; rank < 8; ++rank) {
      float best = -3.4e38f;
      int bi = 0;
      for (int c = 0; c < Me; ++c) {
        float v = xs[r][c];
        if (!((taken >> c) & 1ull) && v > best) { best = v; bi = c; }
      }
      taken |= (1ull << bi);
      out[OFF_TOPC_IDX + grow * 8 + rank] = (float)bi;
      if (rank == 0) { tv0 = best; out[OFF_TOPK_IDX + grow * 2 + 0] = (float)bi; }
      if (rank == 1) { tv1 = best; out[OFF_TOPK_IDX + grow * 2 + 1] = (float)bi; }
    }

    // topk_weights = stable_softmax([tv0, tv1]) with tv0 >= tv1
    const float e1  = expf(tv1 - tv0);
    const float den = 1.f + e1 + 1e-12f;
    out[OFF_TOPK_W + grow * 2 + 0] = 1.f / den;
    out[OFF_TOPK_W + grow * 2 + 1] = e1 / den;
  }
}

extern "C" void kernel_launch(void* const* d_in, const int* in_sizes, int n_in,
                              void* d_out, int out_size, void* d_ws, size_t ws_size,
                              hipStream_t stream) {
  const float* x = (const float*)d_in[0];
  const float* W = (const float*)d_in[1];
  float* out = (float*)d_out;

  dim3 grid(Bq / BM);   // 512 blocks
  dim3 block(256);
  hipLaunchKernelGGL(gating_fused, grid, block, 0, stream, x, W, out);
}

// Round 2
// 125.581 us; speedup vs baseline: 1.2453x; 1.2453x over previous
//
#include <hip/hip_runtime.h>

// GatingNetwork: router GEMM via 3-term bf16-split MFMA + fused softmax/double top-k
// x: [16384, 2048] f32, W: [64, 2048] f32
// out (f32 flat): topk_idx[16384,2] | topk_weights[16384,2] | probs[16384,64] | topc_idx[16384,8]

typedef __attribute__((ext_vector_type(8))) short short8;   // 8 bf16 = 4 VGPR (MFMA A/B frag)
typedef __attribute__((ext_vector_type(4))) float f32x4;    // MFMA C/D frag

constexpr int Bq = 16384;
constexpr int Dk = 2048;
constexpr int Me = 64;

constexpr size_t OFF_TOPK_IDX = 0;
constexpr size_t OFF_TOPK_W   = (size_t)Bq * 2;
constexpr size_t OFF_PROBS    = (size_t)Bq * 4;
constexpr size_t OFF_TOPC_IDX = (size_t)Bq * 4 + (size_t)Bq * 64;

__device__ __forceinline__ unsigned short bf16_rne(float f) {
  unsigned u = __float_as_uint(f);
  return (unsigned short)((u + 0x7FFFu + ((u >> 16) & 1u)) >> 16);
}
__device__ __forceinline__ float bf16_up(unsigned short h) {
  return __uint_as_float(((unsigned)h) << 16);
}

// ---- prep: split W f32 -> 3 bf16 planes in workspace ----
__global__ void wsplit_kernel(const float* __restrict__ W,
                              unsigned short* __restrict__ w0,
                              unsigned short* __restrict__ w1,
                              unsigned short* __restrict__ w2) {
  int i = blockIdx.x * blockDim.x + threadIdx.x;  // float4 index, 32768 total
  float4 v = reinterpret_cast<const float4*>(W)[i];
  float f[4] = {v.x, v.y, v.z, v.w};
  unsigned short a0[4], a1[4], a2[4];
  #pragma unroll
  for (int j = 0; j < 4; ++j) {
    unsigned short b0 = bf16_rne(f[j]);
    float r1 = f[j] - bf16_up(b0);
    unsigned short b1 = bf16_rne(r1);
    float r2 = r1 - bf16_up(b1);
    unsigned short b2 = bf16_rne(r2);
    a0[j] = b0; a1[j] = b1; a2[j] = b2;
  }
  ulong1 dummy; (void)dummy;
  reinterpret_cast<uint2*>(w0)[i] = *reinterpret_cast<uint2*>(a0);
  reinterpret_cast<uint2*>(w1)[i] = *reinterpret_cast<uint2*>(a1);
  reinterpret_cast<uint2*>(w2)[i] = *reinterpret_cast<uint2*>(a2);
}

// ---- main: 1 wave per block, 16 rows x 64 experts, K=2048 ----
__global__ __launch_bounds__(64)
void gating_mfma(const float* __restrict__ x,
                 const unsigned short* __restrict__ w0,
                 const unsigned short* __restrict__ w1,
                 const unsigned short* __restrict__ w2,
                 float* __restrict__ out) {
  __shared__ float l_log[16][66];  // logits
  __shared__ float l_exp[16][66];  // exp(logit - max)

  const int L    = threadIdx.x;   // 0..63
  const int lidx = L & 15;        // A: row within M-tile; B: col within N-tile
  const int kgrp = L >> 4;        // k-octet group 0..3
  const int rowBase = blockIdx.x * 16;

  const float* ax = x + (size_t)(rowBase + lidx) * Dk + kgrp * 8;
  const size_t boff = (size_t)lidx * Dk + kgrp * 8;

  f32x4 acc[4];
  #pragma unroll
  for (int n = 0; n < 4; ++n) acc[n] = (f32x4){0.f, 0.f, 0.f, 0.f};

  // prefetch first A octet (8 f32 per lane)
  float4 aLo = *reinterpret_cast<const float4*>(ax);
  float4 aHi = *reinterpret_cast<const float4*>(ax + 4);

  #pragma unroll 1
  for (int k0 = 0; k0 < Dk; k0 += 32) {
    // prefetch next A (clamped; last-iter value unused)
    const int kn = (k0 + 32 < Dk) ? (k0 + 32) : 0;
    float4 nLo = *reinterpret_cast<const float4*>(ax + kn);
    float4 nHi = *reinterpret_cast<const float4*>(ax + kn + 4);

    // B fragments: 3 versions x 4 N-tiles (bf16, L1/L2-hot)
    short8 b0[4], b1[4], b2[4];
    #pragma unroll
    for (int n = 0; n < 4; ++n) {
      const size_t o = (size_t)n * 16 * Dk + boff + k0;
      b0[n] = *reinterpret_cast<const short8*>(w0 + o);
      b1[n] = *reinterpret_cast<const short8*>(w1 + o);
      b2[n] = *reinterpret_cast<const short8*>(w2 + o);
    }

    // split current A octet into 3 bf16 fragments
    float af[8] = {aLo.x, aLo.y, aLo.z, aLo.w, aHi.x, aHi.y, aHi.z, aHi.w};
    short8 xa0, xa1, xa2;
    #pragma unroll
    for (int j = 0; j < 8; ++j) {
      unsigned short c0 = bf16_rne(af[j]);
      float r1 = af[j] - bf16_up(c0);
      unsigned short c1 = bf16_rne(r1);
      float r2 = r1 - bf16_up(c1);
      unsigned short c2 = bf16_rne(r2);
      xa0[j] = (short)c0; xa1[j] = (short)c1; xa2[j] = (short)c2;
    }

    // 6 products: x0W0 x1W0 x2W0 x0W1 x1W1 x0W2 (>= 2^-18 terms)
    #pragma unroll
    for (int n = 0; n < 4; ++n) acc[n] = __builtin_amdgcn_mfma_f32_16x16x32_bf16(xa0, b0[n], acc[n], 0, 0, 0);
    #pragma unroll
    for (int n = 0; n < 4; ++n) acc[n] = __builtin_amdgcn_mfma_f32_16x16x32_bf16(xa1, b0[n], acc[n], 0, 0, 0);
    #pragma unroll
    for (int n = 0; n < 4; ++n) acc[n] = __builtin_amdgcn_mfma_f32_16x16x32_bf16(xa2, b0[n], acc[n], 0, 0, 0);
    #pragma unroll
    for (int n = 0; n < 4; ++n) acc[n] = __builtin_amdgcn_mfma_f32_16x16x32_bf16(xa0, b1[n], acc[n], 0, 0, 0);
    #pragma unroll
    for (int n = 0; n < 4; ++n) acc[n] = __builtin_amdgcn_mfma_f32_16x16x32_bf16(xa1, b1[n], acc[n], 0, 0, 0);
    #pragma unroll
    for (int n = 0; n < 4; ++n) acc[n] = __builtin_amdgcn_mfma_f32_16x16x32_bf16(xa0, b2[n], acc[n], 0, 0, 0);

    aLo = nLo; aHi = nHi;
  }

  // scatter D: col = lane&15, row = (lane>>4)*4 + reg  [m89-verified]
  #pragma unroll
  for (int n = 0; n < 4; ++n)
    #pragma unroll
    for (int r = 0; r < 4; ++r)
      l_log[kgrp * 4 + r][n * 16 + lidx] = acc[n][r];
  __syncthreads();

  if (L < 16) {
    const int r = L;
    const size_t grow = (size_t)rowBase + r;

    float mx = -3.4e38f;
    for (int c = 0; c < Me; ++c) mx = fmaxf(mx, l_log[r][c]);
    float sum = 0.f;
    for (int c = 0; c < Me; ++c) {
      float e = expf(l_log[r][c] - mx);
      sum += e;
      l_exp[r][c] = e;
    }
    const float inv = 1.f / (sum + 1e-12f);
    float* pr = out + OFF_PROBS + grow * 64;
    for (int c = 0; c < Me; ++c) pr[c] = l_exp[r][c] * inv;

    // top-8 masked argmax on LOGITS (ascending scan + strict '>' = lowest-index tie-break)
    unsigned long long taken = 0ull;
    float tv0 = 0.f, tv1 = 0.f;
    for (int rank = 0; rank < 8; ++rank) {
      float best = -3.4e38f;
      int bi = 0;
      for (int c = 0; c < Me; ++c) {
        float v = l_log[r][c];
        if (!((taken >> c) & 1ull) && v > best) { best = v; bi = c; }
      }
      taken |= (1ull << bi);
      out[OFF_TOPC_IDX + grow * 8 + rank] = (float)bi;
      if (rank == 0) { tv0 = best; out[OFF_TOPK_IDX + grow * 2 + 0] = (float)bi; }
      if (rank == 1) { tv1 = best; out[OFF_TOPK_IDX + grow * 2 + 1] = (float)bi; }
    }

    const float e1  = expf(tv1 - tv0);
    const float den = 1.f + e1 + 1e-12f;
    out[OFF_TOPK_W + grow * 2 + 0] = 1.f / den;
    out[OFF_TOPK_W + grow * 2 + 1] = e1 / den;
  }
}

extern "C" void kernel_launch(void* const* d_in, const int* in_sizes, int n_in,
                              void* d_out, int out_size, void* d_ws, size_t ws_size,
                              hipStream_t stream) {
  const float* x = (const float*)d_in[0];
  const float* W = (const float*)d_in[1];
  float* out = (float*)d_out;

  unsigned short* w0 = (unsigned short*)d_ws;
  unsigned short* w1 = w0 + (size_t)Me * Dk;
  unsigned short* w2 = w1 + (size_t)Me * Dk;

  hipLaunchKernelGGL(wsplit_kernel, dim3((Me * Dk / 4) / 256), dim3(256), 0, stream, W, w0, w1, w2);
  hipLaunchKernelGGL(gating_mfma, dim3(Bq / 16), dim3(64), 0, stream, x, w0, w1, w2, out);
}

// Round 3
// 114.849 us; speedup vs baseline: 1.3617x; 1.0934x over previous
//
#include <hip/hip_runtime.h>

// GatingNetwork: router GEMM via 3-term bf16-split MFMA + fused softmax/double top-k
// Round 3: 4-way K-split per block (4 waves, LDS reduce) for occupancy; parallel epilogue.
// x: [16384, 2048] f32, W: [64, 2048] f32
// out (f32 flat): topk_idx[16384,2] | topk_weights[16384,2] | probs[16384,64] | topc_idx[16384,8]

typedef __attribute__((ext_vector_type(8))) short short8;   // 8 bf16 = 4 VGPR (MFMA A/B frag)
typedef __attribute__((ext_vector_type(4))) float f32x4;    // MFMA C/D frag

constexpr int Bq = 2048 * 8;   // 16384 rows
constexpr int Dk = 2048;
constexpr int Me = 64;
constexpr int KSPLIT = 4;
constexpr int KCHUNK = Dk / KSPLIT;  // 512

constexpr size_t OFF_TOPK_IDX = 0;
constexpr size_t OFF_TOPK_W   = (size_t)Bq * 2;
constexpr size_t OFF_PROBS    = (size_t)Bq * 4;
constexpr size_t OFF_TOPC_IDX = (size_t)Bq * 4 + (size_t)Bq * 64;

__device__ __forceinline__ unsigned short bf16_rne(float f) {
  unsigned u = __float_as_uint(f);
  return (unsigned short)((u + 0x7FFFu + ((u >> 16) & 1u)) >> 16);
}
__device__ __forceinline__ float bf16_up(unsigned short h) {
  return __uint_as_float(((unsigned)h) << 16);
}

// ---- prep: split W f32 -> 3 bf16 planes in workspace ----
__global__ void wsplit_kernel(const float* __restrict__ W,
                              unsigned short* __restrict__ w0,
                              unsigned short* __restrict__ w1,
                              unsigned short* __restrict__ w2) {
  int i = blockIdx.x * blockDim.x + threadIdx.x;  // float4 index, 32768 total
  float4 v = reinterpret_cast<const float4*>(W)[i];
  float f[4] = {v.x, v.y, v.z, v.w};
  unsigned short a0[4], a1[4], a2[4];
  #pragma unroll
  for (int j = 0; j < 4; ++j) {
    unsigned short b0 = bf16_rne(f[j]);
    float r1 = f[j] - bf16_up(b0);
    unsigned short b1 = bf16_rne(r1);
    float r2 = r1 - bf16_up(b1);
    a0[j] = b0; a1[j] = b1; a2[j] = bf16_rne(r2);
  }
  reinterpret_cast<uint2*>(w0)[i] = *reinterpret_cast<uint2*>(a0);
  reinterpret_cast<uint2*>(w1)[i] = *reinterpret_cast<uint2*>(a1);
  reinterpret_cast<uint2*>(w2)[i] = *reinterpret_cast<uint2*>(a2);
}

// ---- main: 256 threads = 4 waves; each wave = same 16 rows, 1/4 of K ----
__global__ __launch_bounds__(256)
void gating_mfma(const float* __restrict__ x,
                 const unsigned short* __restrict__ w0,
                 const unsigned short* __restrict__ w1,
                 const unsigned short* __restrict__ w2,
                 float* __restrict__ out) {
  __shared__ float part[KSPLIT][16][68];  // per-wave partial logits (68: pad, 2-way banks max)

  const int tid  = threadIdx.x;
  const int wv   = tid >> 6;      // wave id = K-chunk id
  const int L    = tid & 63;
  const int lidx = L & 15;        // A: row within tile; B: expert within N-tile
  const int kgrp = L >> 4;        // k-octet group 0..3
  const int rowBase = blockIdx.x * 16;
  const int kBase = wv * KCHUNK;

  const float* ax = x + (size_t)(rowBase + lidx) * Dk + kBase + kgrp * 8;
  const size_t boff = (size_t)lidx * Dk + kBase + kgrp * 8;

  f32x4 acc[4];
  #pragma unroll
  for (int n = 0; n < 4; ++n) acc[n] = (f32x4){0.f, 0.f, 0.f, 0.f};

  float4 aLo = *reinterpret_cast<const float4*>(ax);
  float4 aHi = *reinterpret_cast<const float4*>(ax + 4);

  #pragma unroll 1
  for (int k0 = 0; k0 < KCHUNK; k0 += 32) {
    const int kn = (k0 + 32 < KCHUNK) ? (k0 + 32) : 0;
    float4 nLo = *reinterpret_cast<const float4*>(ax + kn);
    float4 nHi = *reinterpret_cast<const float4*>(ax + kn + 4);

    short8 b0[4], b1[4], b2[4];
    #pragma unroll
    for (int n = 0; n < 4; ++n) {
      const size_t o = (size_t)n * 16 * Dk + boff + k0;
      b0[n] = *reinterpret_cast<const short8*>(w0 + o);
      b1[n] = *reinterpret_cast<const short8*>(w1 + o);
      b2[n] = *reinterpret_cast<const short8*>(w2 + o);
    }

    float af[8] = {aLo.x, aLo.y, aLo.z, aLo.w, aHi.x, aHi.y, aHi.z, aHi.w};
    short8 xa0, xa1, xa2;
    #pragma unroll
    for (int j = 0; j < 8; ++j) {
      unsigned short c0 = bf16_rne(af[j]);
      float r1 = af[j] - bf16_up(c0);
      unsigned short c1 = bf16_rne(r1);
      float r2 = r1 - bf16_up(c1);
      xa0[j] = (short)c0; xa1[j] = (short)c1; xa2[j] = (short)bf16_rne(r2);
    }

    // 6 products: x0W0 x1W0 x2W0 x0W1 x1W1 x0W2
    #pragma unroll
    for (int n = 0; n < 4; ++n) acc[n] = __builtin_amdgcn_mfma_f32_16x16x32_bf16(xa0, b0[n], acc[n], 0, 0, 0);
    #pragma unroll
    for (int n = 0; n < 4; ++n) acc[n] = __builtin_amdgcn_mfma_f32_16x16x32_bf16(xa1, b0[n], acc[n], 0, 0, 0);
    #pragma unroll
    for (int n = 0; n < 4; ++n) acc[n] = __builtin_amdgcn_mfma_f32_16x16x32_bf16(xa2, b0[n], acc[n], 0, 0, 0);
    #pragma unroll
    for (int n = 0; n < 4; ++n) acc[n] = __builtin_amdgcn_mfma_f32_16x16x32_bf16(xa0, b1[n], acc[n], 0, 0, 0);
    #pragma unroll
    for (int n = 0; n < 4; ++n) acc[n] = __builtin_amdgcn_mfma_f32_16x16x32_bf16(xa1, b1[n], acc[n], 0, 0, 0);
    #pragma unroll
    for (int n = 0; n < 4; ++n) acc[n] = __builtin_amdgcn_mfma_f32_16x16x32_bf16(xa0, b2[n], acc[n], 0, 0, 0);

    aLo = nLo; aHi = nHi;
  }

  // scatter partial D: col = lane&15 (+16n), row = (lane>>4)*4 + reg  [m89-verified]
  #pragma unroll
  for (int n = 0; n < 4; ++n)
    #pragma unroll
    for (int r = 0; r < 4; ++r)
      part[wv][kgrp * 4 + r][n * 16 + lidx] = acc[n][r];
  __syncthreads();

  // ---- epilogue: 16 threads per row, each owns 4 logit columns ----
  const int row = (tid >> 6) * 4 + ((tid & 63) >> 4);  // 0..15
  const int g   = tid & 15;                            // 16-lane subgroup position
  const int c4  = g * 4;
  const size_t grow = (size_t)rowBase + row;

  float4 v = {0.f, 0.f, 0.f, 0.f};
  #pragma unroll
  for (int p = 0; p < KSPLIT; ++p) {
    float4 t = *reinterpret_cast<const float4*>(&part[p][row][c4]);
    v.x += t.x; v.y += t.y; v.z += t.z; v.w += t.w;
  }
  float pv[4] = {v.x, v.y, v.z, v.w};

  // softmax over 64 via width-16 butterflies (masks <16 stay within row-group)
  float mx = fmaxf(fmaxf(pv[0], pv[1]), fmaxf(pv[2], pv[3]));
  #pragma unroll
  for (int m = 1; m < 16; m <<= 1) mx = fmaxf(mx, __shfl_xor(mx, m));
  float e[4], sum = 0.f;
  #pragma unroll
  for (int j = 0; j < 4; ++j) { e[j] = expf(pv[j] - mx); sum += e[j]; }
  #pragma unroll
  for (int m = 1; m < 16; m <<= 1) sum += __shfl_xor(sum, m);
  const float inv = 1.f / (sum + 1e-12f);
  float4 pw = {e[0] * inv, e[1] * inv, e[2] * inv, e[3] * inv};
  *reinterpret_cast<float4*>(out + OFF_PROBS + grow * 64 + c4) = pw;

  // top-8: 8 masked argmax passes; tie-break = lowest index (matches jax/np)
  unsigned taken = 0;
  int bidx0 = 0, bidx1 = 0;
  float tv0 = 0.f, tv1 = 0.f;
  #pragma unroll 1
  for (int rank = 0; rank < 8; ++rank) {
    float best = -3.4e38f;
    int bl = -1;
    #pragma unroll
    for (int j = 0; j < 4; ++j)
      if (!((taken >> j) & 1u) && pv[j] > best) { best = pv[j]; bl = j; }
    int bidx = (bl >= 0) ? (c4 + bl) : (1 << 30);
    #pragma unroll
    for (int m = 1; m < 16; m <<= 1) {
      float ov = __shfl_xor(best, m);
      int   oi = __shfl_xor(bidx, m);
      if (ov > best || (ov == best && oi < bidx)) { best = ov; bidx = oi; }
    }
    if (bidx >= c4 && bidx < c4 + 4) taken |= 1u << (bidx - c4);
    if (g == 0) out[OFF_TOPC_IDX + grow * 8 + rank] = (float)bidx;
    if (rank == 0) { tv0 = best; bidx0 = bidx; }
    if (rank == 1) { tv1 = best; bidx1 = bidx; }
  }

  if (g == 0) {
    out[OFF_TOPK_IDX + grow * 2 + 0] = (float)bidx0;
    out[OFF_TOPK_IDX + grow * 2 + 1] = (float)bidx1;
    const float e1  = expf(tv1 - tv0);
    const float den = 1.f + e1 + 1e-12f;
    out[OFF_TOPK_W + grow * 2 + 0] = 1.f / den;
    out[OFF_TOPK_W + grow * 2 + 1] = e1 / den;
  }
}

extern "C" void kernel_launch(void* const* d_in, const int* in_sizes, int n_in,
                              void* d_out, int out_size, void* d_ws, size_t ws_size,
                              hipStream_t stream) {
  const float* x = (const float*)d_in[0];
  const float* W = (const float*)d_in[1];
  float* out = (float*)d_out;

  unsigned short* w0 = (unsigned short*)d_ws;
  unsigned short* w1 = w0 + (size_t)Me * Dk;
  unsigned short* w2 = w1 + (size_t)Me * Dk;

  hipLaunchKernelGGL(wsplit_kernel, dim3((Me * Dk / 4) / 256), dim3(256), 0, stream, W, w0, w1, w2);
  hipLaunchKernelGGL(gating_mfma, dim3(Bq / 16), dim3(256), 0, stream, x, w0, w1, w2, out);
}

// Round 5
// 53.242 us; speedup vs baseline: 2.9373x; 2.1571x over previous
//
#include <hip/hip_runtime.h>

// GatingNetwork: router GEMM via 3-term bf16-split MFMA + fused softmax/double top-k
// Round 5: round-4 design with compile fix (inline-asm v_cvt_pk_bf16_f32 instead of
// __hip_bfloat162 bit_cast). W fragment-repacked (1KB/instr contiguous loads);
// x staged through per-wave LDS double-buffer; packed cvt bf16 split.
// x: [16384, 2048] f32, W: [64, 2048] f32
// out (f32 flat): topk_idx[16384,2] | topk_weights[16384,2] | probs[16384,64] | topc_idx[16384,8]

typedef __attribute__((ext_vector_type(8))) short short8;   // 8 bf16 = 4 VGPR (MFMA A/B frag)
typedef __attribute__((ext_vector_type(4))) float f32x4;    // MFMA C/D frag

constexpr int Bq = 16384;
constexpr int Dk = 2048;
constexpr int Me = 64;
constexpr int KSPLIT = 4;
constexpr int KCHUNK = Dk / KSPLIT;   // 512
constexpr int NT = KCHUNK / 32;       // 16 k-tiles per wave

constexpr size_t OFF_TOPK_IDX = 0;
constexpr size_t OFF_TOPK_W   = (size_t)Bq * 2;
constexpr size_t OFF_PROBS    = (size_t)Bq * 4;
constexpr size_t OFF_TOPC_IDX = (size_t)Bq * 4 + (size_t)Bq * 64;

// packed f32x2 -> 2 bf16 (RNE, v_cvt_pk_bf16_f32); low16 = lo, high16 = hi
__device__ __forceinline__ unsigned f2bf2(float lo, float hi) {
  unsigned r;
  asm("v_cvt_pk_bf16_f32 %0, %1, %2" : "=v"(r) : "v"(lo), "v"(hi));
  return r;
}
__device__ __forceinline__ float bflo(unsigned u) { return __builtin_bit_cast(float, u << 16); }
__device__ __forceinline__ float bfhi(unsigned u) { return __builtin_bit_cast(float, u & 0xFFFF0000u); }

// split 8 f32 -> 3 short8 bf16 fragments (telescoping residuals)
__device__ __forceinline__ void split3(const float af[8], short8& s0, short8& s1, short8& s2) {
  uint4 q0, q1, q2;
  unsigned* p0 = &q0.x; unsigned* p1 = &q1.x; unsigned* p2 = &q2.x;
  #pragma unroll
  for (int p = 0; p < 4; ++p) {
    float a = af[2 * p], b = af[2 * p + 1];
    unsigned c0 = f2bf2(a, b);
    float r0a = a - bflo(c0), r0b = b - bfhi(c0);
    unsigned c1 = f2bf2(r0a, r0b);
    float r1a = r0a - bflo(c1), r1b = r0b - bfhi(c1);
    unsigned c2 = f2bf2(r1a, r1b);
    p0[p] = c0; p1[p] = c1; p2[p] = c2;
  }
  s0 = __builtin_bit_cast(short8, q0);
  s1 = __builtin_bit_cast(short8, q1);
  s2 = __builtin_bit_cast(short8, q2);
}

// ---- prep: split W f32 -> 3 bf16 planes, FRAGMENT-PACKED: [kt][n][lane][8] ----
// element (kt,n,L,j) = W[n*16 + (L&15)][kt*32 + (L>>4)*8 + j]
__global__ void wsplit_kernel(const float* __restrict__ W,
                              unsigned short* __restrict__ w0,
                              unsigned short* __restrict__ w1,
                              unsigned short* __restrict__ w2) {
  int t = blockIdx.x * blockDim.x + threadIdx.x;  // 0..16383
  int kt = t >> 8, n = (t >> 6) & 3, L = t & 63;
  int e  = n * 16 + (L & 15);
  int kb = kt * 32 + ((L >> 4) << 3);
  const float* src = W + (size_t)e * Dk + kb;
  float4 a = *reinterpret_cast<const float4*>(src);
  float4 b = *reinterpret_cast<const float4*>(src + 4);
  float af[8] = {a.x, a.y, a.z, a.w, b.x, b.y, b.z, b.w};
  short8 s0, s1, s2;
  split3(af, s0, s1, s2);
  *reinterpret_cast<short8*>(w0 + (size_t)t * 8) = s0;
  *reinterpret_cast<short8*>(w1 + (size_t)t * 8) = s1;
  *reinterpret_cast<short8*>(w2 + (size_t)t * 8) = s2;
}

// ---- main: 256 threads = 4 waves; each wave = same 16 rows, 1/4 of K ----
__global__ __launch_bounds__(256, 4)
void gating_mfma(const float* __restrict__ x,
                 const unsigned short* __restrict__ w0,
                 const unsigned short* __restrict__ w1,
                 const unsigned short* __restrict__ w2,
                 float* __restrict__ out) {
  // overlay: A-stage [2][4][16][36] f32 (18432B) then part [4][16][68] f32 (17408B)
  __shared__ __align__(16) char smem[2 * 4 * 16 * 36 * 4];
  typedef float XaT[4][16][36];
  XaT* xa = reinterpret_cast<XaT*>(smem);                               // xa[buf][wv][row][col]
  typedef float PartT[16][68];
  PartT* part = reinterpret_cast<PartT*>(smem);                         // part[wv][row][col]

  const int tid  = threadIdx.x;
  const int wv   = tid >> 6;      // wave id = K-chunk id
  const int L    = tid & 63;
  const int lidx = L & 15;        // A: row within tile; B: expert within N-tile
  const int kgrp = L >> 4;        // k-octet group 0..3
  const int rowBase = blockIdx.x * 16;
  const int kBase = wv * KCHUNK;

  // staging lane mapping: instr i covers rows i*8..i*8+7, 128B contiguous per row
  const int srow0 = L >> 3;          // 0..7
  const int srow1 = 8 + srow0;       // 8..15
  const int sc4   = (L & 7) << 2;    // f32 col 0,4,..,28
  const float* xg0 = x + (size_t)(rowBase + srow0) * Dk + kBase + sc4;
  const float* xg1 = x + (size_t)(rowBase + srow1) * Dk + kBase + sc4;

  // B fragment base (shorts): tile kt -> kt*2048 + n*512 + L*8
  const size_t bbase = (size_t)kBase * 64 + (size_t)L * 8;

  f32x4 acc[4];
  #pragma unroll
  for (int n = 0; n < 4; ++n) acc[n] = (f32x4){0.f, 0.f, 0.f, 0.f};

  // prologue: tile0 -> LDS buf0; tile1 -> hold regs
  {
    float4 t0a = *reinterpret_cast<const float4*>(xg0);
    float4 t0b = *reinterpret_cast<const float4*>(xg1);
    *reinterpret_cast<float4*>(&xa[0][wv][srow0][sc4]) = t0a;
    *reinterpret_cast<float4*>(&xa[0][wv][srow1][sc4]) = t0b;
  }
  float4 hA = *reinterpret_cast<const float4*>(xg0 + 32);
  float4 hB = *reinterpret_cast<const float4*>(xg1 + 32);

  #pragma unroll 2
  for (int kt = 0; kt < NT; ++kt) {
    // A fragment: lane (lidx,kgrp) reads row lidx, k = kt*32 + kgrp*8..+8
    float4 fLo = *reinterpret_cast<const float4*>(&xa[kt & 1][wv][lidx][kgrp * 8]);
    float4 fHi = *reinterpret_cast<const float4*>(&xa[kt & 1][wv][lidx][kgrp * 8 + 4]);

    // B fragments: contiguous 1KB per instruction
    const size_t to = bbase + (size_t)kt * 2048;
    short8 b0[4], b1[4], b2[4];
    #pragma unroll
    for (int n = 0; n < 4; ++n) {
      b0[n] = *reinterpret_cast<const short8*>(w0 + to + n * 512);
      b1[n] = *reinterpret_cast<const short8*>(w1 + to + n * 512);
      b2[n] = *reinterpret_cast<const short8*>(w2 + to + n * 512);
    }

    // ds_write tile kt+1 (held in regs) into the other buffer
    if (kt < NT - 1) {
      *reinterpret_cast<float4*>(&xa[(kt + 1) & 1][wv][srow0][sc4]) = hA;
      *reinterpret_cast<float4*>(&xa[(kt + 1) & 1][wv][srow1][sc4]) = hB;
    }
    // prefetch tile kt+2 global -> hold regs (2-iteration slack)
    if (kt < NT - 2) {
      hA = *reinterpret_cast<const float4*>(xg0 + (kt + 2) * 32);
      hB = *reinterpret_cast<const float4*>(xg1 + (kt + 2) * 32);
    }

    // split A octet into 3 bf16 fragments (packed cvt)
    float af[8] = {fLo.x, fLo.y, fLo.z, fLo.w, fHi.x, fHi.y, fHi.z, fHi.w};
    short8 xa0, xa1, xa2;
    split3(af, xa0, xa1, xa2);

    // 6 products: x0W0 x1W0 x2W0 x0W1 x1W1 x0W2
    #pragma unroll
    for (int n = 0; n < 4; ++n) acc[n] = __builtin_amdgcn_mfma_f32_16x16x32_bf16(xa0, b0[n], acc[n], 0, 0, 0);
    #pragma unroll
    for (int n = 0; n < 4; ++n) acc[n] = __builtin_amdgcn_mfma_f32_16x16x32_bf16(xa1, b0[n], acc[n], 0, 0, 0);
    #pragma unroll
    for (int n = 0; n < 4; ++n) acc[n] = __builtin_amdgcn_mfma_f32_16x16x32_bf16(xa2, b0[n], acc[n], 0, 0, 0);
    #pragma unroll
    for (int n = 0; n < 4; ++n) acc[n] = __builtin_amdgcn_mfma_f32_16x16x32_bf16(xa0, b1[n], acc[n], 0, 0, 0);
    #pragma unroll
    for (int n = 0; n < 4; ++n) acc[n] = __builtin_amdgcn_mfma_f32_16x16x32_bf16(xa1, b1[n], acc[n], 0, 0, 0);
    #pragma unroll
    for (int n = 0; n < 4; ++n) acc[n] = __builtin_amdgcn_mfma_f32_16x16x32_bf16(xa0, b2[n], acc[n], 0, 0, 0);
  }

  // all waves must be done reading xa before part overlays it
  __syncthreads();

  // scatter partial D: col = lane&15 (+16n), row = (lane>>4)*4 + reg  [m89-verified]
  #pragma unroll
  for (int n = 0; n < 4; ++n)
    #pragma unroll
    for (int r = 0; r < 4; ++r)
      part[wv][kgrp * 4 + r][n * 16 + lidx] = acc[n][r];
  __syncthreads();

  // ---- epilogue: 16 threads per row, each owns 4 logit columns ----
  const int row = (tid >> 6) * 4 + ((tid & 63) >> 4);  // 0..15
  const int g   = tid & 15;
  const int c4  = g * 4;
  const size_t grow = (size_t)rowBase + row;

  float4 v = {0.f, 0.f, 0.f, 0.f};
  #pragma unroll
  for (int p = 0; p < KSPLIT; ++p) {
    float4 t = *reinterpret_cast<const float4*>(&part[p][row][c4]);
    v.x += t.x; v.y += t.y; v.z += t.z; v.w += t.w;
  }
  float pv[4] = {v.x, v.y, v.z, v.w};

  // softmax over 64 via width-16 butterflies
  float mx = fmaxf(fmaxf(pv[0], pv[1]), fmaxf(pv[2], pv[3]));
  #pragma unroll
  for (int m = 1; m < 16; m <<= 1) mx = fmaxf(mx, __shfl_xor(mx, m));
  float e[4], sum = 0.f;
  #pragma unroll
  for (int j = 0; j < 4; ++j) { e[j] = expf(pv[j] - mx); sum += e[j]; }
  #pragma unroll
  for (int m = 1; m < 16; m <<= 1) sum += __shfl_xor(sum, m);
  const float inv = 1.f / (sum + 1e-12f);
  float4 pw = {e[0] * inv, e[1] * inv, e[2] * inv, e[3] * inv};
  *reinterpret_cast<float4*>(out + OFF_PROBS + grow * 64 + c4) = pw;

  // top-8: 8 masked argmax passes; tie-break = lowest index (matches jax/np)
  unsigned taken = 0;
  int bidx0 = 0, bidx1 = 0;
  float tv0 = 0.f, tv1 = 0.f;
  #pragma unroll 1
  for (int rank = 0; rank < 8; ++rank) {
    float best = -3.4e38f;
    int bl = -1;
    #pragma unroll
    for (int j = 0; j < 4; ++j)
      if (!((taken >> j) & 1u) && pv[j] > best) { best = pv[j]; bl = j; }
    int bidx = (bl >= 0) ? (c4 + bl) : (1 << 30);
    #pragma unroll
    for (int m = 1; m < 16; m <<= 1) {
      float ov = __shfl_xor(best, m);
      int   oi = __shfl_xor(bidx, m);
      if (ov > best || (ov == best && oi < bidx)) { best = ov; bidx = oi; }
    }
    if (bidx >= c4 && bidx < c4 + 4) taken |= 1u << (bidx - c4);
    if (g == 0) out[OFF_TOPC_IDX + grow * 8 + rank] = (float)bidx;
    if (rank == 0) { tv0 = best; bidx0 = bidx; }
    if (rank == 1) { tv1 = best; bidx1 = bidx; }
  }

  if (g == 0) {
    out[OFF_TOPK_IDX + grow * 2 + 0] = (float)bidx0;
    out[OFF_TOPK_IDX + grow * 2 + 1] = (float)bidx1;
    const float e1  = expf(tv1 - tv0);
    const float den = 1.f + e1 + 1e-12f;
    out[OFF_TOPK_W + grow * 2 + 0] = 1.f / den;
    out[OFF_TOPK_W + grow * 2 + 1] = e1 / den;
  }
}

extern "C" void kernel_launch(void* const* d_in, const int* in_sizes, int n_in,
                              void* d_out, int out_size, void* d_ws, size_t ws_size,
                              hipStream_t stream) {
  const float* x = (const float*)d_in[0];
  const float* W = (const float*)d_in[1];
  float* out = (float*)d_out;

  unsigned short* w0 = (unsigned short*)d_ws;
  unsigned short* w1 = w0 + (size_t)Me * Dk;
  unsigned short* w2 = w1 + (size_t)Me * Dk;

  hipLaunchKernelGGL(wsplit_kernel, dim3((Me * Dk / 8) / 256), dim3(256), 0, stream, W, w0, w1, w2);
  hipLaunchKernelGGL(gating_mfma, dim3(Bq / 16), dim3(256), 0, stream, x, w0, w1, w2, out);
}

// Round 6
// 46.430 us; speedup vs baseline: 3.3682x; 1.1467x over previous
//
#include <hip/hip_runtime.h>

// GatingNetwork: router GEMM via 3-term bf16-split MFMA + fused softmax/double top-k
// Round 6: 32 rows/wave (halves B traffic to 384 MB), 8-wave blocks, K-split 8,
// single-buffered per-wave A staging (write-late), per-plane B load interleave.
// x: [16384, 2048] f32, W: [64, 2048] f32
// out (f32 flat): topk_idx[16384,2] | topk_weights[16384,2] | probs[16384,64] | topc_idx[16384,8]

typedef __attribute__((ext_vector_type(8))) short short8;   // 8 bf16 = 4 VGPR (MFMA A/B frag)
typedef __attribute__((ext_vector_type(4))) float f32x4;    // MFMA C/D frag

constexpr int Bq = 16384;
constexpr int Dk = 2048;
constexpr int Me = 64;
constexpr int WAVES = 8;
constexpr int ROWS = 32;             // rows per block (all waves share them)
constexpr int KCHUNK = Dk / WAVES;   // 256
constexpr int NT = KCHUNK / 32;      // 8 k-tiles per wave

constexpr size_t OFF_TOPK_IDX = 0;
constexpr size_t OFF_TOPK_W   = (size_t)Bq * 2;
constexpr size_t OFF_PROBS    = (size_t)Bq * 4;
constexpr size_t OFF_TOPC_IDX = (size_t)Bq * 4 + (size_t)Bq * 64;

// packed f32x2 -> 2 bf16 (RNE, v_cvt_pk_bf16_f32); low16 = lo, high16 = hi
__device__ __forceinline__ unsigned f2bf2(float lo, float hi) {
  unsigned r;
  asm("v_cvt_pk_bf16_f32 %0, %1, %2" : "=v"(r) : "v"(lo), "v"(hi));
  return r;
}
__device__ __forceinline__ float bflo(unsigned u) { return __builtin_bit_cast(float, u << 16); }
__device__ __forceinline__ float bfhi(unsigned u) { return __builtin_bit_cast(float, u & 0xFFFF0000u); }

// split 8 f32 -> 3 short8 bf16 fragments (telescoping residuals)
__device__ __forceinline__ void split3(const float af[8], short8& s0, short8& s1, short8& s2) {
  uint4 q0, q1, q2;
  unsigned* p0 = &q0.x; unsigned* p1 = &q1.x; unsigned* p2 = &q2.x;
  #pragma unroll
  for (int p = 0; p < 4; ++p) {
    float a = af[2 * p], b = af[2 * p + 1];
    unsigned c0 = f2bf2(a, b);
    float r0a = a - bflo(c0), r0b = b - bfhi(c0);
    unsigned c1 = f2bf2(r0a, r0b);
    float r1a = r0a - bflo(c1), r1b = r0b - bfhi(c1);
    unsigned c2 = f2bf2(r1a, r1b);
    p0[p] = c0; p1[p] = c1; p2[p] = c2;
  }
  s0 = __builtin_bit_cast(short8, q0);
  s1 = __builtin_bit_cast(short8, q1);
  s2 = __builtin_bit_cast(short8, q2);
}

// ---- prep: split W f32 -> 3 bf16 planes, FRAGMENT-PACKED: [kt][n][lane][8] ----
// element (kt,n,L,j) = W[n*16 + (L&15)][kt*32 + (L>>4)*8 + j]
__global__ void wsplit_kernel(const float* __restrict__ W,
                              unsigned short* __restrict__ w0,
                              unsigned short* __restrict__ w1,
                              unsigned short* __restrict__ w2) {
  int t = blockIdx.x * blockDim.x + threadIdx.x;  // 0..16383
  int kt = t >> 8, n = (t >> 6) & 3, L = t & 63;
  int e  = n * 16 + (L & 15);
  int kb = kt * 32 + ((L >> 4) << 3);
  const float* src = W + (size_t)e * Dk + kb;
  float4 a = *reinterpret_cast<const float4*>(src);
  float4 b = *reinterpret_cast<const float4*>(src + 4);
  float af[8] = {a.x, a.y, a.z, a.w, b.x, b.y, b.z, b.w};
  short8 s0, s1, s2;
  split3(af, s0, s1, s2);
  *reinterpret_cast<short8*>(w0 + (size_t)t * 8) = s0;
  *reinterpret_cast<short8*>(w1 + (size_t)t * 8) = s1;
  *reinterpret_cast<short8*>(w2 + (size_t)t * 8) = s2;
}

// ---- main: 512 threads = 8 waves; all waves share 32 rows, each owns 1/8 of K ----
__global__ __launch_bounds__(512, 4)
void gating_mfma(const float* __restrict__ x,
                 const unsigned short* __restrict__ w0,
                 const unsigned short* __restrict__ w1,
                 const unsigned short* __restrict__ w2,
                 float* __restrict__ out) {
  // overlay: A-stage xa[8][32][36] f32 (36864B) then part[8][32][64] f32 (65536B)
  __shared__ __align__(16) char smem[WAVES * ROWS * 64 * 4];  // 65536
  typedef float XaT[ROWS][36];
  XaT* xa = reinterpret_cast<XaT*>(smem);        // xa[wv][row][col]
  typedef float PartT[ROWS][64];
  PartT* part = reinterpret_cast<PartT*>(smem);  // part[wv][row][col]

  const int tid  = threadIdx.x;
  const int wv   = tid >> 6;      // wave id = K-chunk id (0..7)
  const int L    = tid & 63;
  const int lidx = L & 15;        // A: row within 16-group; B: expert within N-tile
  const int kgrp = L >> 4;        // k-octet group 0..3
  const int rowBase = blockIdx.x * ROWS;
  const int kBase = wv * KCHUNK;

  // staging lane mapping: segment i covers rows i*8..i*8+7, 128B contiguous per row
  const int srow = L >> 3;           // 0..7
  const int sc4  = (L & 7) << 2;     // f32 col 0,4,..,28
  const float* xg0 = x + (size_t)(rowBase +      srow) * Dk + kBase + sc4;
  const float* xg1 = x + (size_t)(rowBase +  8 + srow) * Dk + kBase + sc4;
  const float* xg2 = x + (size_t)(rowBase + 16 + srow) * Dk + kBase + sc4;
  const float* xg3 = x + (size_t)(rowBase + 24 + srow) * Dk + kBase + sc4;

  // B fragment base (shorts): global tile ktg -> ktg*2048 + n*512 + L*8
  const size_t bbase = (size_t)kBase * 64 + (size_t)L * 8;

  f32x4 acc[2][4];
  #pragma unroll
  for (int rg = 0; rg < 2; ++rg)
    #pragma unroll
    for (int n = 0; n < 4; ++n) acc[rg][n] = (f32x4){0.f, 0.f, 0.f, 0.f};

  // prologue: tile0 -> LDS (wave-private region, no barrier needed)
  *reinterpret_cast<float4*>(&xa[wv][     srow][sc4]) = *reinterpret_cast<const float4*>(xg0);
  *reinterpret_cast<float4*>(&xa[wv][ 8 + srow][sc4]) = *reinterpret_cast<const float4*>(xg1);
  *reinterpret_cast<float4*>(&xa[wv][16 + srow][sc4]) = *reinterpret_cast<const float4*>(xg2);
  *reinterpret_cast<float4*>(&xa[wv][24 + srow][sc4]) = *reinterpret_cast<const float4*>(xg3);

  #pragma unroll 1
  for (int kt = 0; kt < NT; ++kt) {
    // A fragments for both row-groups (reads complete before the write-late below)
    float4 aLo0 = *reinterpret_cast<const float4*>(&xa[wv][     lidx][kgrp * 8]);
    float4 aHi0 = *reinterpret_cast<const float4*>(&xa[wv][     lidx][kgrp * 8 + 4]);
    float4 aLo1 = *reinterpret_cast<const float4*>(&xa[wv][16 + lidx][kgrp * 8]);
    float4 aHi1 = *reinterpret_cast<const float4*>(&xa[wv][16 + lidx][kgrp * 8 + 4]);

    // issue next-tile global loads early (latency hides under MFMA; written late)
    float4 h0, h1, h2, h3;
    if (kt < NT - 1) {
      h0 = *reinterpret_cast<const float4*>(xg0 + (kt + 1) * 32);
      h1 = *reinterpret_cast<const float4*>(xg1 + (kt + 1) * 32);
      h2 = *reinterpret_cast<const float4*>(xg2 + (kt + 1) * 32);
      h3 = *reinterpret_cast<const float4*>(xg3 + (kt + 1) * 32);
    }

    const size_t to = bbase + (size_t)kt * 2048;

    // plane-0 B loads
    short8 b0[4];
    #pragma unroll
    for (int n = 0; n < 4; ++n) b0[n] = *reinterpret_cast<const short8*>(w0 + to + n * 512);

    // split both A octets into 3 bf16 fragments each
    float af0[8] = {aLo0.x, aLo0.y, aLo0.z, aLo0.w, aHi0.x, aHi0.y, aHi0.z, aHi0.w};
    float af1[8] = {aLo1.x, aLo1.y, aLo1.z, aLo1.w, aHi1.x, aHi1.y, aHi1.z, aHi1.w};
    short8 xs00, xs10, xs20, xs01, xs11, xs21;   // xs<plane><rowgroup>
    split3(af0, xs00, xs10, xs20);
    split3(af1, xs01, xs11, xs21);

    // plane-1 B loads issued before plane-0 MFMA cluster (latency overlap)
    short8 b1[4];
    #pragma unroll
    for (int n = 0; n < 4; ++n) b1[n] = *reinterpret_cast<const short8*>(w1 + to + n * 512);

    // plane 0: x0*W0, x1*W0, x2*W0 for both row-groups (24 MFMA)
    #pragma unroll
    for (int n = 0; n < 4; ++n) acc[0][n] = __builtin_amdgcn_mfma_f32_16x16x32_bf16(xs00, b0[n], acc[0][n], 0, 0, 0);
    #pragma unroll
    for (int n = 0; n < 4; ++n) acc[1][n] = __builtin_amdgcn_mfma_f32_16x16x32_bf16(xs01, b0[n], acc[1][n], 0, 0, 0);
    #pragma unroll
    for (int n = 0; n < 4; ++n) acc[0][n] = __builtin_amdgcn_mfma_f32_16x16x32_bf16(xs10, b0[n], acc[0][n], 0, 0, 0);
    #pragma unroll
    for (int n = 0; n < 4; ++n) acc[1][n] = __builtin_amdgcn_mfma_f32_16x16x32_bf16(xs11, b0[n], acc[1][n], 0, 0, 0);
    #pragma unroll
    for (int n = 0; n < 4; ++n) acc[0][n] = __builtin_amdgcn_mfma_f32_16x16x32_bf16(xs20, b0[n], acc[0][n], 0, 0, 0);
    #pragma unroll
    for (int n = 0; n < 4; ++n) acc[1][n] = __builtin_amdgcn_mfma_f32_16x16x32_bf16(xs21, b0[n], acc[1][n], 0, 0, 0);

    // plane-2 B loads issued before plane-1 MFMA cluster
    short8 b2[4];
    #pragma unroll
    for (int n = 0; n < 4; ++n) b2[n] = *reinterpret_cast<const short8*>(w2 + to + n * 512);

    // plane 1: x0*W1, x1*W1 (16 MFMA)
    #pragma unroll
    for (int n = 0; n < 4; ++n) acc[0][n] = __builtin_amdgcn_mfma_f32_16x16x32_bf16(xs00, b1[n], acc[0][n], 0, 0, 0);
    #pragma unroll
    for (int n = 0; n < 4; ++n) acc[1][n] = __builtin_amdgcn_mfma_f32_16x16x32_bf16(xs01, b1[n], acc[1][n], 0, 0, 0);
    #pragma unroll
    for (int n = 0; n < 4; ++n) acc[0][n] = __builtin_amdgcn_mfma_f32_16x16x32_bf16(xs10, b1[n], acc[0][n], 0, 0, 0);
    #pragma unroll
    for (int n = 0; n < 4; ++n) acc[1][n] = __builtin_amdgcn_mfma_f32_16x16x32_bf16(xs11, b1[n], acc[1][n], 0, 0, 0);

    // plane 2: x0*W2 (8 MFMA)
    #pragma unroll
    for (int n = 0; n < 4; ++n) acc[0][n] = __builtin_amdgcn_mfma_f32_16x16x32_bf16(xs00, b2[n], acc[0][n], 0, 0, 0);
    #pragma unroll
    for (int n = 0; n < 4; ++n) acc[1][n] = __builtin_amdgcn_mfma_f32_16x16x32_bf16(xs01, b2[n], acc[1][n], 0, 0, 0);

    // write-late: next A tile into the (single) wave-private buffer
    if (kt < NT - 1) {
      *reinterpret_cast<float4*>(&xa[wv][     srow][sc4]) = h0;
      *reinterpret_cast<float4*>(&xa[wv][ 8 + srow][sc4]) = h1;
      *reinterpret_cast<float4*>(&xa[wv][16 + srow][sc4]) = h2;
      *reinterpret_cast<float4*>(&xa[wv][24 + srow][sc4]) = h3;
    }
  }

  // all waves done with xa before part overlays it
  __syncthreads();

  // scatter partial D: row = rg*16 + kgrp*4 + r, col = n*16 + lidx  [m89-verified]
  #pragma unroll
  for (int rg = 0; rg < 2; ++rg)
    #pragma unroll
    for (int n = 0; n < 4; ++n)
      #pragma unroll
      for (int r = 0; r < 4; ++r)
        part[wv][rg * 16 + kgrp * 4 + r][n * 16 + lidx] = acc[rg][n][r];
  __syncthreads();

  // ---- epilogue: 16 threads per row, each owns 4 logit columns ----
  const int row = tid >> 4;        // 0..31
  const int g   = tid & 15;
  const int c4  = g * 4;
  const size_t grow = (size_t)rowBase + row;

  float4 v = {0.f, 0.f, 0.f, 0.f};
  #pragma unroll
  for (int p = 0; p < WAVES; ++p) {
    float4 t = *reinterpret_cast<const float4*>(&part[p][row][c4]);
    v.x += t.x; v.y += t.y; v.z += t.z; v.w += t.w;
  }
  float pv[4] = {v.x, v.y, v.z, v.w};

  // softmax over 64 via width-16 butterflies
  float mx = fmaxf(fmaxf(pv[0], pv[1]), fmaxf(pv[2], pv[3]));
  #pragma unroll
  for (int m = 1; m < 16; m <<= 1) mx = fmaxf(mx, __shfl_xor(mx, m));
  float e[4], sum = 0.f;
  #pragma unroll
  for (int j = 0; j < 4; ++j) { e[j] = expf(pv[j] - mx); sum += e[j]; }
  #pragma unroll
  for (int m = 1; m < 16; m <<= 1) sum += __shfl_xor(sum, m);
  const float inv = 1.f / (sum + 1e-12f);
  float4 pw = {e[0] * inv, e[1] * inv, e[2] * inv, e[3] * inv};
  *reinterpret_cast<float4*>(out + OFF_PROBS + grow * 64 + c4) = pw;

  // top-8: 8 masked argmax passes; tie-break = lowest index (matches jax/np)
  unsigned taken = 0;
  int bidx0 = 0, bidx1 = 0;
  float tv0 = 0.f, tv1 = 0.f;
  #pragma unroll 1
  for (int rank = 0; rank < 8; ++rank) {
    float best = -3.4e38f;
    int bl = -1;
    #pragma unroll
    for (int j = 0; j < 4; ++j)
      if (!((taken >> j) & 1u) && pv[j] > best) { best = pv[j]; bl = j; }
    int bidx = (bl >= 0) ? (c4 + bl) : (1 << 30);
    #pragma unroll
    for (int m = 1; m < 16; m <<= 1) {
      float ov = __shfl_xor(best, m);
      int   oi = __shfl_xor(bidx, m);
      if (ov > best || (ov == best && oi < bidx)) { best = ov; bidx = oi; }
    }
    if (bidx >= c4 && bidx < c4 + 4) taken |= 1u << (bidx - c4);
    if (g == 0) out[OFF_TOPC_IDX + grow * 8 + rank] = (float)bidx;
    if (rank == 0) { tv0 = best; bidx0 = bidx; }
    if (rank == 1) { tv1 = best; bidx1 = bidx; }
  }

  if (g == 0) {
    out[OFF_TOPK_IDX + grow * 2 + 0] = (float)bidx0;
    out[OFF_TOPK_IDX + grow * 2 + 1] = (float)bidx1;
    const float e1  = expf(tv1 - tv0);
    const float den = 1.f + e1 + 1e-12f;
    out[OFF_TOPK_W + grow * 2 + 0] = 1.f / den;
    out[OFF_TOPK_W + grow * 2 + 1] = e1 / den;
  }
}

extern "C" void kernel_launch(void* const* d_in, const int* in_sizes, int n_in,
                              void* d_out, int out_size, void* d_ws, size_t ws_size,
                              hipStream_t stream) {
  const float* x = (const float*)d_in[0];
  const float* W = (const float*)d_in[1];
  float* out = (float*)d_out;

  unsigned short* w0 = (unsigned short*)d_ws;
  unsigned short* w1 = w0 + (size_t)Me * Dk;
  unsigned short* w2 = w1 + (size_t)Me * Dk;

  hipLaunchKernelGGL(wsplit_kernel, dim3((Me * Dk / 8) / 256), dim3(256), 0, stream, W, w0, w1, w2);
  hipLaunchKernelGGL(gating_mfma, dim3(Bq / ROWS), dim3(512), 0, stream, x, w0, w1, w2, out);
}